// Round 1
// baseline (146.192 us; speedup 1.0000x reference)
//
#include <hip/hip_runtime.h>
#include <stdint.h>
#include <math.h>

#define TPB   512    // 8 waves/block -> 4 blocks/CU hits the 32-wave cap
#define KTOP  100
#define K1    128    // selection rank cut (per-slice in s1, per-image in s2)
#define KSLOT 192    // per-slice emitted u32 slots (>= K1 + tie-bin margin)
#define CAP   768    // stage-1 survivor capacity (expected ~450/slice, +13 sigma)
#define SR    8      // slice rows
#define AMB   512    // ambiguous-tie queue capacity (expected ~190/slice; inline fallback on overflow)

#define HB 272
#define WB 480
#define NSB 34       // 272/8
#define HP 68
#define WP 120
#define NSP 9        // ceil(68/8), last slice 4 rows
#define NB 64

// ============================================================================
// Validated invariants (rounds 2-5, absmax 0.0):
//  - np-f32 softmax p is a MONOTONE function G of D = fl32(x1-x0);
//    G collapse window |dD| < ~6e-8*e^|D| (< 0.25 for |D| < 13).
//  - NMS: keep iff p >= all 8 neighbors; D-space fast path + exact G on ties.
//  - top-k tie order: (p desc, idx asc)  ==  u64 key (p_bits<<32 | ~idx) desc.
//  - 16-bit D-key rank-128 cut contains the exact top-100 set.
// R6: ambiguous ties are DEFERRED to an LDS queue and resolved in one dense
//     sweep (all lanes active) instead of inline in the NMS loop, where wave
//     divergence made ~96% of cell-steps execute the masked f64-exp path.
//     Decision function is bit-identical; surv order differs (irrelevant:
//     surv is an unordered selection buffer, stage2 re-ranks exactly).
// ============================================================================
__device__ __forceinline__ float G_exact(float D) {
    float t = -fabsf(D);
    float etf = (float)exp((double)t);       // correctly-rounded f32 exp
    return (D > 0.0f) ? __fdiv_rn(1.0f, __fadd_rn(etf, 1.0f))
                      : __fdiv_rn(etf, __fadd_rn(1.0f, etf));
}

__device__ __forceinline__ uint32_t flip_f32(float D) {
    uint32_t u = __float_as_uint(D);
    return (u & 0x80000000u) ? ~u : (u | 0x80000000u);
}

// In-place suffix-sum of 256 u32 bins: hist[i] <- sum_{j>=i} hist[j].
// Wave 0 via shuffles; ends with a barrier. (validated round 4)
__device__ __forceinline__ void suffix_scan_256(uint32_t* hist) {
    if (threadIdx.x < 64) {
        int lane = threadIdx.x;
        uint32_t h0 = hist[4*lane+0], h1 = hist[4*lane+1];
        uint32_t h2 = hist[4*lane+2], h3 = hist[4*lane+3];
        uint32_t tot = h0 + h1 + h2 + h3;
        uint32_t run = tot;
        #pragma unroll
        for (int d = 1; d < 64; d <<= 1) {
            uint32_t o = __shfl_down(run, d, 64);
            if (lane + d < 64) run += o;
        }
        uint32_t ab = run - tot;
        hist[4*lane+3] = ab + h3;
        hist[4*lane+2] = ab + h3 + h2;
        hist[4*lane+1] = ab + h3 + h2 + h1;
        hist[4*lane+0] = ab + tot;
    }
    __syncthreads();
}

// Descending bitonic sort of 256 u64 keys; TPB may exceed 256 (guarded).
__device__ void bitonic_sort_256(uint64_t* keys) {
    for (int k = 2; k <= 256; k <<= 1) {
        for (int j = k >> 1; j > 0; j >>= 1) {
            int i = threadIdx.x;
            if (i < 256) {
                int ixj = i ^ j;
                if (ixj > i) {
                    uint64_t ka = keys[i], kb = keys[ixj];
                    bool sw = ((ka < kb) == ((i & k) == 0));
                    if (sw) { keys[i] = kb; keys[ixj] = ka; }
                }
            }
            __syncthreads();
        }
    }
}

// 6-wide row window [c4-1 .. c4+4] from the LDS D-tile (OOB -> -inf).
template<int W>
__device__ __forceinline__ void row6(const float* df, int row, int c4, float* a) {
    const float4 m = ((const float4*)df)[(row * W + c4) >> 2];
    a[1] = m.x; a[2] = m.y; a[3] = m.z; a[4] = m.w;
    a[0] = (c4 > 0)     ? df[row * W + c4 - 1] : -INFINITY;
    a[5] = (c4 + 4 < W) ? df[row * W + c4 + 4] : -INFINITY;
}

// ---- stage 1 body: NMS + D16 radix-select, emit u32 slots ------------------
// Templated W/H/NS -> all divisions become compile-time magic-mul/shift.
template<int H, int W, int NS>
__device__ __forceinline__ void stage1_impl(const float* __restrict__ x,
                                            int s, int b,
                                            uint32_t* __restrict__ key_out,
                                            unsigned char* smem)
{
    constexpr int W4 = W / 4;
    constexpr int tileRows = SR + 2;
    const int r0 = s * SR;
    const int rows = (H - r0 < SR) ? (H - r0) : SR;

    float*    df   = (float*)smem;                         // tileRows * W
    uint32_t* surv = (uint32_t*)(df + tileRows * W);       // CAP
    uint32_t* hist = surv + CAP;                           // 256
    uint32_t* outb = hist + 256;                           // KSLOT
    uint32_t* ambp = outb + KSLOT;                         // AMB (packed lr|c)
    float*    ambv = (float*)(ambp + AMB);                 // AMB (v)
    float*    ambm = ambv + AMB;                           // AMB (mx)
    __shared__ int s_cnt, s_out, s_amb;
    __shared__ uint32_t s_bin, s_ab, s_bin2, s_none;
    if (threadIdx.x == 0) { s_cnt = 0; s_out = 0; s_none = 0; s_amb = 0; }
    if (threadIdx.x < 256) hist[threadIdx.x] = 0;

    const float*  x0  = x + (size_t)b * 2 * H * W;
    const float*  x1  = x0 + (size_t)H * W;
    const float4* x0v = (const float4*)x0;
    const float4* x1v = (const float4*)x1;
    float4* dfv = (float4*)df;

    // D tile (rows r0-1 .. r0+SR), float4-vectorized; OOB rows -> -inf.
    constexpr int nt4 = tileRows * W4;
    for (int t = threadIdx.x; t < nt4; t += TPB) {
        int tr = t / W4, c4 = t - tr * W4;        // compile-time divisor
        int r = r0 - 1 + tr;
        float4 d4 = make_float4(-INFINITY, -INFINITY, -INFINITY, -INFINITY);
        if (r >= 0 && r < H) {
            float4 a = x0v[r * W4 + c4];
            float4 c = x1v[r * W4 + c4];
            d4.x = __fsub_rn(c.x, a.x);
            d4.y = __fsub_rn(c.y, a.y);
            d4.z = __fsub_rn(c.z, a.z);
            d4.w = __fsub_rn(c.w, a.w);
        }
        dfv[t] = d4;
    }
    __syncthreads();

    // NMS (4 cells/iter) + level-1 histogram fused into the keep path.
    // Ambiguous ties (rare per lane, but ~every wave-step inline) go to the
    // deferred queue; resolved densely after the loop.
    const int groups = rows * W4;
    for (int g = threadIdx.x; g < groups; g += TPB) {
        int lr = g / W4, c4 = (g - lr * W4) << 2; // compile-time divisor
        int tr = lr + 1;
        float ap[6], ac[6], an[6];
        row6<W>(df, tr - 1, c4, ap);
        row6<W>(df, tr,     c4, ac);
        row6<W>(df, tr + 1, c4, an);
        #pragma unroll
        for (int j = 0; j < 4; ++j) {
            float v = ac[j + 1];
            float mx = fmaxf(fmaxf(fmaxf(ap[j], ap[j+1]), fmaxf(ap[j+2], an[j])),
                             fmaxf(fmaxf(an[j+1], an[j+2]), fmaxf(ac[j], ac[j+2])));
            bool keep = false;
            if (v >= mx) keep = true;                              // exact
            else if (mx - v >= 0.25f && mx < 13.0f) keep = false;  // G distinct
            else {
                int qp = atomicAdd(&s_amb, 1);
                if (qp < AMB) {                                    // defer (hot path)
                    ambp[qp] = ((uint32_t)lr << 9) | (uint32_t)(c4 + j);
                    ambv[qp] = v;
                    ambm[qp] = mx;
                } else {                                           // overflow: inline exact
                    keep = (G_exact(v) == G_exact(mx));
                }
            }
            if (keep) {
                uint32_t key16 = flip_f32(v) >> 16;
                int pos = atomicAdd(&s_cnt, 1);
                if (pos < CAP)
                    surv[pos] = (key16 << 16) | ((uint32_t)lr << 9) | (uint32_t)(c4 + j);
                atomicAdd(&hist[key16 >> 8], 1u);
            }
        }
    }
    __syncthreads();

    // Dense resolution of deferred ties: all lanes active, ~1 iteration.
    const int namb = (s_amb < AMB) ? s_amb : AMB;
    for (int t = threadIdx.x; t < namb; t += TPB) {
        float v = ambv[t], mx = ambm[t];
        if (G_exact(v) == G_exact(mx)) {
            uint32_t key16 = flip_f32(v) >> 16;
            int pos = atomicAdd(&s_cnt, 1);
            if (pos < CAP)
                surv[pos] = (key16 << 16) | ambp[t];
            atomicAdd(&hist[key16 >> 8], 1u);
        }
    }
    __syncthreads();
    const int n = (s_cnt < CAP) ? s_cnt : CAP;

    // Level-1 select on D16 high byte.
    suffix_scan_256(hist);
    if (threadIdx.x < 256) {
        uint32_t si = hist[threadIdx.x];
        uint32_t sn = (threadIdx.x < 255) ? hist[threadIdx.x + 1] : 0u;
        if (threadIdx.x == 0 && si < K1) s_none = 1;
        if (si >= K1 && sn < K1) { s_bin = threadIdx.x; s_ab = sn; }
    }
    __syncthreads();

    uint32_t T16 = 0;
    if (!s_none) {
        const uint32_t b3 = s_bin;
        const uint32_t k2 = K1 - s_ab;
        if (threadIdx.x < 256) hist[threadIdx.x] = 0;
        __syncthreads();
        for (int t = threadIdx.x; t < n; t += TPB) {
            uint32_t sv = surv[t];
            if ((sv >> 24) == b3) atomicAdd(&hist[(sv >> 16) & 255u], 1u);
        }
        __syncthreads();
        suffix_scan_256(hist);
        if (threadIdx.x < 256) {
            uint32_t si = hist[threadIdx.x];
            uint32_t sn = (threadIdx.x < 255) ? hist[threadIdx.x + 1] : 0u;
            if (si >= k2 && sn < k2) s_bin2 = threadIdx.x;
        }
        __syncthreads();
        T16 = (b3 << 8) | s_bin2;
    }

    // Compact survivors with D16 >= T16 (unsorted), zero-padded to KSLOT.
    if (threadIdx.x < KSLOT) outb[threadIdx.x] = 0;
    __syncthreads();
    for (int t = threadIdx.x; t < n; t += TPB) {
        uint32_t sv = surv[t];
        if ((sv >> 16) >= T16) {
            int pos = atomicAdd(&s_out, 1);
            if (pos < KSLOT) outb[pos] = sv;
        }
    }
    __syncthreads();
    if (threadIdx.x < KSLOT)
        key_out[((size_t)b * NS + s) * KSLOT + threadIdx.x] = outb[threadIdx.x];
}

__global__ __launch_bounds__(TPB) void stage1(const float* __restrict__ bmap,
                                              const float* __restrict__ pmap,
                                              uint32_t* __restrict__ bkey,
                                              uint32_t* __restrict__ pkey)
{
    extern __shared__ unsigned char smem[];
    if (blockIdx.x < NSB)
        stage1_impl<HB, WB, NSB>(bmap, blockIdx.x, blockIdx.y, bkey, smem);
    else
        stage1_impl<HP, WP, NSP>(pmap, blockIdx.x - NSB, blockIdx.y, pkey, smem);
}

// ---- stage 2 body: D16 select -> exact-p re-rank of <=256 -> decode --------
template<int H, int W, int NS, bool BALL>
__device__ __forceinline__ void stage2_impl(const float* __restrict__ xmap,
                                            const float* __restrict__ pbbox,
                                            const uint32_t* __restrict__ key_in,
                                            float* __restrict__ outp,
                                            int b, unsigned char* smem)
{
    constexpr int M = NS * KSLOT;
    const float* x0 = xmap + (size_t)b * 2 * H * W;
    const float* x1 = x0 + (size_t)H * W;
    const uint32_t* kin = key_in + (size_t)b * M;

    uint32_t* keys = (uint32_t*)smem;           // M
    uint32_t* hist = keys + M;                  // 256
    uint64_t* outb = (uint64_t*)(hist + 256);   // 256
    __shared__ int s_out;
    __shared__ uint32_t s_bin, s_ab, s_bin2, s_none;
    if (threadIdx.x == 0) { s_out = 0; s_none = 0; }
    if (threadIdx.x < 256) hist[threadIdx.x] = 0;
    __syncthreads();

    // Load keys + level-1 histogram in one pass.
    for (int t = threadIdx.x; t < M; t += TPB) {
        uint32_t k = kin[t];
        keys[t] = k;
        if (k) atomicAdd(&hist[k >> 24], 1u);
    }
    __syncthreads();
    suffix_scan_256(hist);
    if (threadIdx.x < 256) {
        uint32_t si = hist[threadIdx.x];
        uint32_t sn = (threadIdx.x < 255) ? hist[threadIdx.x + 1] : 0u;
        if (threadIdx.x == 0 && si < K1) s_none = 1;
        if (si >= K1 && sn < K1) { s_bin = threadIdx.x; s_ab = sn; }
    }
    __syncthreads();

    uint32_t T16 = 0;
    if (!s_none) {
        const uint32_t b3 = s_bin;
        const uint32_t k2 = K1 - s_ab;
        if (threadIdx.x < 256) hist[threadIdx.x] = 0;
        __syncthreads();
        for (int t = threadIdx.x; t < M; t += TPB) {
            uint32_t k = keys[t];
            if (k && (k >> 24) == b3) atomicAdd(&hist[(k >> 16) & 255u], 1u);
        }
        __syncthreads();
        suffix_scan_256(hist);
        if (threadIdx.x < 256) {
            uint32_t si = hist[threadIdx.x];
            uint32_t sn = (threadIdx.x < 255) ? hist[threadIdx.x + 1] : 0u;
            if (si >= k2 && sn < k2) s_bin2 = threadIdx.x;
        }
        __syncthreads();
        T16 = (b3 << 8) | s_bin2;
    }

    // Compact finalists; compute exact np p only here (D re-read from map).
    if (threadIdx.x < 256) outb[threadIdx.x] = 0;
    __syncthreads();
    for (int t = threadIdx.x; t < M; t += TPB) {
        uint32_t k = keys[t];
        if (k && (k >> 16) >= T16) {
            int pos = atomicAdd(&s_out, 1);
            if (pos < 256) {
                int sIdx = t / KSLOT;                      // compile-time divisor
                int lr = (k >> 9) & 7, c = k & 511;
                int gidx = (sIdx * SR + lr) * W + c;
                float D = __fsub_rn(x1[gidx], x0[gidx]);
                float p = G_exact(D);
                outb[pos] = ((uint64_t)__float_as_uint(p) << 32) | (uint32_t)(~gidx);
            }
        }
    }
    __syncthreads();
    bitonic_sort_256(outb);

    // Decode top-100 (exact (p desc, idx asc) order).
    if (threadIdx.x < KTOP) {
        uint64_t k = outb[threadIdx.x];
        int id = (int)(~(uint32_t)k);
        float o0 = 0.f, o1 = 0.f, o2 = 0.f, o3 = 0.f, val = 0.f;
        if ((unsigned)id < (unsigned)(H * W)) {
            val = __uint_as_float((uint32_t)(k >> 32));
            int yy = id / W, xx = id - yy * W;             // compile-time divisor
            constexpr float ds = BALL ? 4.0f : 16.0f;
            float xc = (float)xx * ds + (ds - 1.0f) * 0.5f;
            float yc = (float)yy * ds + (ds - 1.0f) * 0.5f;
            float t0 = 0.f, t1 = 0.f;
            float t2 = BALL ? 40.0f : 0.0f, t3 = BALL ? 40.0f : 0.0f;
            if (!BALL) {
                const float* bb = pbbox + (size_t)b * 4 * H * W;
                constexpr float sx = (float)W * ds, sy = (float)H * ds;
                t0 = bb[id]             * sx;
                t1 = bb[id + H * W]     * sy;
                t2 = bb[id + 2 * H * W] * sx;
                t3 = bb[id + 3 * H * W] * sy;
            }
            float bx = xc + t0, by = yc + t1;
            o0 = bx - 0.5f * t2;
            o1 = by - 0.5f * t3;
            o2 = bx + 0.5f * t2;
            o3 = by + 0.5f * t3;
        }
        float* op = outp + (size_t)threadIdx.x * 5;
        op[0] = o0; op[1] = o1; op[2] = o2; op[3] = o3; op[4] = val;
    }
}

__global__ __launch_bounds__(TPB) void stage2(const float* __restrict__ bmap,
                                              const float* __restrict__ pmap,
                                              const float* __restrict__ pbbox,
                                              const uint32_t* __restrict__ bkey,
                                              const uint32_t* __restrict__ pkey,
                                              float* __restrict__ out)
{
    extern __shared__ unsigned char smem[];
    if (blockIdx.x < NB) {
        int b = blockIdx.x;
        stage2_impl<HB, WB, NSB, true>(bmap, nullptr, bkey,
            out + (size_t)NB * KTOP * 5 + (size_t)b * KTOP * 5, b, smem);
    } else {
        int b = blockIdx.x - NB;
        stage2_impl<HP, WP, NSP, false>(pmap, pbbox, pkey,
            out + (size_t)b * KTOP * 5, b, smem);
    }
}

// ---- launch -----------------------------------------------------------------
extern "C" void kernel_launch(void* const* d_in, const int* in_sizes, int n_in,
                              void* d_out, int out_size, void* d_ws, size_t ws_size,
                              hipStream_t stream) {
    const float* pmap  = (const float*)d_in[0];   // [64,2,68,120]
    const float* pbbox = (const float*)d_in[1];   // [64,4,68,120]
    const float* bmap  = (const float*)d_in[2];   // [64,2,272,480]
    float* out = (float*)d_out;                   // player [64,100,5] then ball

    uint32_t* ws_bkey = (uint32_t*)d_ws;                       // 64*34*192 u32
    uint32_t* ws_pkey = ws_bkey + (size_t)NB * NSB * KSLOT;    // 64*9*192 u32
    // total ws: 2,113,536 B (within proven budget)

    // LDS: tile 19200 + surv 3072 + hist 1024 + outb 768 + amb 6144 = 30208 B
    // -> still 4 blk/CU (wave-capped; 4*30208 = 120832 < 163840)
    size_t lds1 = (size_t)(SR + 2) * WB * 4 + (size_t)CAP * 4 + 1024
                + (size_t)KSLOT * 4 + (size_t)AMB * 12;
    stage1<<<dim3(NSB + NSP, NB), TPB, lds1, stream>>>(bmap, pmap, ws_bkey, ws_pkey);

    // LDS: keys 26112 + hist 1024 + outb 2048 = 29184 B
    size_t lds2 = (size_t)NSB * KSLOT * 4 + 1024 + 2048;
    stage2<<<2 * NB, TPB, lds2, stream>>>(bmap, pmap, pbbox, ws_bkey, ws_pkey, out);
}